// Round 2
// baseline (483.536 us; speedup 1.0000x reference)
//
#include <hip/hip_runtime.h>

// Problem constants (from reference setup_inputs)
constexpr int B = 16;
constexpr int D = 256;
constexpr int K = 18;
constexpr int SZ = 128;
constexpr int S = SZ * SZ;      // 16384 positions per plane
constexpr int N = S / 2;        // 8192 sampled positions

// LDS proto layout: [4 d-groups][64 rows][K floats], padded:
//  - row stride 20 floats (80 B) keeps float4 reads 16B-aligned
//  - group stride 64*20+8 floats => +8 banks per group, so the 4 per-quad
//    broadcast addresses hit distinct banks (conflict-free)
constexpr int ROWP = 20;
constexpr int GRPP = 64 * ROWP + 8;

// ---------------------------------------------------------------------------
// Phase 2: per sampled position, argmin over K prototypes of squared distance
// d2 = p2[k] - 2*cross[k] (f2 constant over k, dropped).
// Lane-quad d-split: lane = 4*n_local + g; lane g covers d in [g*64,(g+1)*64),
// fp64 partial dots, deterministic 2-step shfl_xor quad reduce.
// ---------------------------------------------------------------------------
__global__ __launch_bounds__(256) void argmin_kernel(
    const float* __restrict__ assp,
    const float* __restrict__ proto,
    const int* __restrict__ idx,
    signed char* __restrict__ table) {
  __shared__ float spf[4 * GRPP];   // ~20.6 KiB
  __shared__ double sp2[K];

  // b = blockIdx % 16 => each batch's blocks share an XCD (xcd = blockIdx % 8)
  const int b  = blockIdx.x & 15;
  const int nb = blockIdx.x >> 4;   // 0..127

  const float* pb = proto + (size_t)b * K * D;
  for (int i = threadIdx.x; i < K * D; i += 256) {
    const int k = i >> 8;           // i / D
    const int d = i & 255;          // i % D
    spf[(d >> 6) * GRPP + (d & 63) * ROWP + k] = pb[i];
  }
  __syncthreads();

  if (threadIdx.x < K) {
    double s = 0.0;
    for (int d = 0; d < D; ++d) {
      const double v = (double)spf[(d >> 6) * GRPP + (d & 63) * ROWP + threadIdx.x];
      s += v * v;
    }
    sp2[threadIdx.x] = s;
  }
  __syncthreads();

  const int lane = threadIdx.x & 63;
  const int wv   = threadIdx.x >> 6;  // wave 0..3
  const int g    = lane & 3;          // d-group 0..3
  const int nl   = lane >> 2;         // 0..15
  const int n    = nb * 64 + wv * 16 + nl;   // 0..8191
  const int pos  = idx[n];                   // 0..16383

  const float* fb   = assp + ((size_t)b * D + g * 64) * S + pos;
  const float* prow = &spf[g * GRPP];

  double acc[K];
#pragma unroll
  for (int k = 0; k < K; ++k) acc[k] = 0.0;

  for (int t = 0; t < 64; t += 8) {
    float fvs[8];
#pragma unroll
    for (int j = 0; j < 8; ++j)
      fvs[j] = fb[(size_t)(t + j) * S];   // 8 independent loads in flight
#pragma unroll
    for (int j = 0; j < 8; ++j) {
      const double fv = (double)fvs[j];
      const float* pr = prow + (t + j) * ROWP;
      const float4 q0 = *(const float4*)(pr + 0);
      const float4 q1 = *(const float4*)(pr + 4);
      const float4 q2 = *(const float4*)(pr + 8);
      const float4 q3 = *(const float4*)(pr + 12);
      const float2 q4 = *(const float2*)(pr + 16);
      acc[0]  += fv * (double)q0.x;  acc[1]  += fv * (double)q0.y;
      acc[2]  += fv * (double)q0.z;  acc[3]  += fv * (double)q0.w;
      acc[4]  += fv * (double)q1.x;  acc[5]  += fv * (double)q1.y;
      acc[6]  += fv * (double)q1.z;  acc[7]  += fv * (double)q1.w;
      acc[8]  += fv * (double)q2.x;  acc[9]  += fv * (double)q2.y;
      acc[10] += fv * (double)q2.z;  acc[11] += fv * (double)q2.w;
      acc[12] += fv * (double)q3.x;  acc[13] += fv * (double)q3.y;
      acc[14] += fv * (double)q3.z;  acc[15] += fv * (double)q3.w;
      acc[16] += fv * (double)q4.x;  acc[17] += fv * (double)q4.y;
    }
  }

  // Deterministic quad reduce: total = (g0+g1) + (g2+g3) per n
#pragma unroll
  for (int k = 0; k < K; ++k) {
    acc[k] += __shfl_xor(acc[k], 1, 64);
    acc[k] += __shfl_xor(acc[k], 2, 64);
  }

  if (g == 0) {
    double best = 1e300;
    int bi = 0;
#pragma unroll
    for (int k = 0; k < K; ++k) {
      const double d2 = sp2[k] - 2.0 * acc[k];
      if (d2 < best) { best = d2; bi = k; }  // strict '<' = first-min (argmin)
    }
    table[(size_t)b * S + pos] = (signed char)bi;
  }
}

// ---------------------------------------------------------------------------
// Phase 3: one block per (b,d) plane. out = in, except table[pos]>=0 =>
// out = proto[b][k][d]. Fully coalesced float4 read/modify/write.
// ---------------------------------------------------------------------------
__global__ __launch_bounds__(256) void scatter_kernel(
    const float* __restrict__ assp,
    const float* __restrict__ proto,
    const signed char* __restrict__ table,
    float* __restrict__ out) {
  const int bd = blockIdx.x;      // 0..B*D-1
  const int b  = bd >> 8;         // /D
  const int d  = bd & 255;        // %D

  __shared__ float sp[K];
  if (threadIdx.x < K)
    sp[threadIdx.x] = proto[((size_t)b * K + threadIdx.x) * D + d];
  __syncthreads();

  const signed char* tb = table + (size_t)b * S;
  const float4* in4 = (const float4*)(assp + (size_t)bd * S);
  float4* out4 = (float4*)(out + (size_t)bd * S);

#pragma unroll
  for (int it = 0; it < S / 4 / 256; ++it) {   // 16 iterations
    const int i = it * 256 + threadIdx.x;      // float4 index within plane
    char4 t;
    *(int*)&t = ((const int*)tb)[i];
    float4 v = in4[i];
    if (t.x >= 0) v.x = sp[(int)t.x];
    if (t.y >= 0) v.y = sp[(int)t.y];
    if (t.z >= 0) v.z = sp[(int)t.z];
    if (t.w >= 0) v.w = sp[(int)t.w];
    out4[i] = v;
  }
}

extern "C" void kernel_launch(void* const* d_in, const int* in_sizes, int n_in,
                              void* d_out, int out_size, void* d_ws, size_t ws_size,
                              hipStream_t stream) {
  const float* assp  = (const float*)d_in[0];
  const float* proto = (const float*)d_in[1];
  const int*   idx   = (const int*)d_in[2];
  float* out = (float*)d_out;
  signed char* table = (signed char*)d_ws;   // B*S = 256 KiB

  // table := -1 everywhere (0xFF == (int8)-1)
  hipMemsetAsync(table, 0xFF, (size_t)B * S, stream);

  argmin_kernel<<<B * (N / 64), 256, 0, stream>>>(assp, proto, idx, table);
  scatter_kernel<<<B * D, 256, 0, stream>>>(assp, proto, table, out);
}

// Round 3
// 211.638 us; speedup vs baseline: 2.2847x; 2.2847x over previous
//
#include <hip/hip_runtime.h>

// Problem constants (from reference setup_inputs)
constexpr int B = 16;
constexpr int D = 256;
constexpr int K = 18;
constexpr int SZ = 128;
constexpr int S = SZ * SZ;      // 16384 positions per plane
constexpr int N = S / 2;        // 8192 sampled positions

// ---------------------------------------------------------------------------
// Prep (1 block): build sampled-position byte mask (shared across batches)
// and p2[b][k] = ||proto_bk||^2 in fp64.
// ---------------------------------------------------------------------------
__global__ __launch_bounds__(512) void prep_kernel(
    const float* __restrict__ proto,
    const int* __restrict__ idx,
    unsigned char* __restrict__ mask,
    double* __restrict__ p2) {
  for (int i = threadIdx.x; i < S; i += 512) mask[i] = 0;
  __syncthreads();
  for (int n = threadIdx.x; n < N; n += 512) mask[idx[n]] = 1;

  // 288 rows; float4 loads, 4 independent fp64 partials for ILP.
  for (int i = threadIdx.x; i < B * K; i += 512) {
    const float4* p = (const float4*)(proto + (size_t)i * D);
    double s0 = 0, s1 = 0, s2 = 0, s3 = 0;
#pragma unroll 4
    for (int q = 0; q < D / 4; ++q) {
      const float4 v = p[q];
      s0 += (double)v.x * (double)v.x;
      s1 += (double)v.y * (double)v.y;
      s2 += (double)v.z * (double)v.z;
      s3 += (double)v.w * (double)v.w;
    }
    p2[i] = (s0 + s1) + (s2 + s3);
  }
}

// ---------------------------------------------------------------------------
// Phase 2 (dense, coalesced): block = (b, 256-position chunk). Each thread
// owns one position s; loops d = 0..255 with fully-coalesced plane reads,
// fp64 FMAs against LDS-resident fp64 prototypes ([d][k], broadcast reads).
// Writes winning k only where mask[s] (table pre-set to -1).
// d-order is sequential 0..255 per k -> summation identical to round 1
// (verified absmax 0.0), so argmin decisions are unchanged.
// ---------------------------------------------------------------------------
__global__ __launch_bounds__(256) void argmin_kernel(
    const float* __restrict__ assp,
    const float* __restrict__ proto,
    const double* __restrict__ p2,
    const unsigned char* __restrict__ mask,
    signed char* __restrict__ table) {
  __shared__ double spd[D][K];    // 36 KiB -> 4 blocks/CU

  const int b     = blockIdx.x & 15;   // xcd = blockIdx%8: batch spread evenly
  const int chunk = blockIdx.x >> 4;   // 0..63

  const float* pb = proto + (size_t)b * K * D;
  for (int i = threadIdx.x; i < K * D; i += 256) {
    const int k = i >> 8;   // i / D
    const int d = i & 255;  // i % D
    spd[d][k] = (double)pb[i];
  }
  __syncthreads();

  const int s = chunk * 256 + threadIdx.x;          // position 0..16383
  const float* fb = assp + (size_t)b * D * S + s;

  double acc[K];
#pragma unroll
  for (int k = 0; k < K; ++k) acc[k] = 0.0;

  for (int d = 0; d < D; d += 8) {
    float fv[8];
#pragma unroll
    for (int j = 0; j < 8; ++j)
      fv[j] = fb[(size_t)(d + j) * S];   // 8 coalesced loads in flight
#pragma unroll
    for (int j = 0; j < 8; ++j) {
      const double f = (double)fv[j];
      const double* pr = spd[d + j];     // wave-uniform -> LDS broadcast
#pragma unroll
      for (int k = 0; k < K; ++k) acc[k] += f * pr[k];
    }
  }

  const double* p2b = p2 + (size_t)b * K;
  double best = 1e300;
  int bi = 0;
#pragma unroll
  for (int k = 0; k < K; ++k) {
    const double d2 = p2b[k] - 2.0 * acc[k];
    if (d2 < best) { best = d2; bi = k; }   // strict '<' = first-min (argmin)
  }

  if (mask[s]) table[(size_t)b * S + s] = (signed char)bi;
}

// ---------------------------------------------------------------------------
// Phase 3: one block per (b,d) plane. out = in, except table[pos]>=0 =>
// out = proto[b][k][d]. Fully coalesced float4 read/modify/write.
// ---------------------------------------------------------------------------
__global__ __launch_bounds__(256) void scatter_kernel(
    const float* __restrict__ assp,
    const float* __restrict__ proto,
    const signed char* __restrict__ table,
    float* __restrict__ out) {
  const int bd = blockIdx.x;      // 0..B*D-1
  const int b  = bd >> 8;         // /D
  const int d  = bd & 255;        // %D

  __shared__ float sp[K];
  if (threadIdx.x < K)
    sp[threadIdx.x] = proto[((size_t)b * K + threadIdx.x) * D + d];
  __syncthreads();

  const signed char* tb = table + (size_t)b * S;
  const float4* in4 = (const float4*)(assp + (size_t)bd * S);
  float4* out4 = (float4*)(out + (size_t)bd * S);

#pragma unroll
  for (int it = 0; it < S / 4 / 256; ++it) {   // 16 iterations
    const int i = it * 256 + threadIdx.x;      // float4 index within plane
    char4 t;
    *(int*)&t = ((const int*)tb)[i];
    float4 v = in4[i];
    if (t.x >= 0) v.x = sp[(int)t.x];
    if (t.y >= 0) v.y = sp[(int)t.y];
    if (t.z >= 0) v.z = sp[(int)t.z];
    if (t.w >= 0) v.w = sp[(int)t.w];
    out4[i] = v;
  }
}

extern "C" void kernel_launch(void* const* d_in, const int* in_sizes, int n_in,
                              void* d_out, int out_size, void* d_ws, size_t ws_size,
                              hipStream_t stream) {
  const float* assp  = (const float*)d_in[0];
  const float* proto = (const float*)d_in[1];
  const int*   idx   = (const int*)d_in[2];
  float* out = (float*)d_out;

  // ws layout: [table: B*S bytes][mask: S bytes][p2: B*K doubles]
  signed char*   table = (signed char*)d_ws;
  unsigned char* mask  = (unsigned char*)d_ws + (size_t)B * S;
  double*        p2    = (double*)((char*)d_ws + (size_t)B * S + S);

  hipMemsetAsync(table, 0xFF, (size_t)B * S, stream);   // table := -1

  prep_kernel<<<1, 512, 0, stream>>>(proto, idx, mask, p2);
  argmin_kernel<<<B * (S / 256), 256, 0, stream>>>(assp, proto, p2, mask, table);
  scatter_kernel<<<B * D, 256, 0, stream>>>(assp, proto, table, out);
}

// Round 5
// 187.855 us; speedup vs baseline: 2.5740x; 1.1266x over previous
//
#include <hip/hip_runtime.h>

// Problem constants (from reference setup_inputs)
constexpr int B = 16;
constexpr int D = 256;
constexpr int K = 18;
constexpr int SZ = 128;
constexpr int S = SZ * SZ;      // 16384 positions per plane
constexpr int N = S / 2;        // 8192 sampled positions

// ---------------------------------------------------------------------------
// Prep (parallel): blocks 0..31 scatter mask ones (mask pre-zeroed by memset);
// blocks 32..103 compute p2[b*K+k] = ||proto||^2 in fp64, one row per warp.
// ---------------------------------------------------------------------------
__global__ __launch_bounds__(256) void prep2_kernel(
    const float* __restrict__ proto,
    const int* __restrict__ idx,
    unsigned char* __restrict__ mask,
    double* __restrict__ p2) {
  const int blk = blockIdx.x;
  if (blk < 32) {
    mask[idx[blk * 256 + threadIdx.x]] = 1;   // indices are a permutation: no conflicts
  } else {
    const int row  = (blk - 32) * 4 + (threadIdx.x >> 6);  // 0..287 = b*K+k
    const int lane = threadIdx.x & 63;
    const float4 v = *(const float4*)(proto + (size_t)row * D + lane * 4);
    double s = (double)v.x * (double)v.x + (double)v.y * (double)v.y
             + (double)v.z * (double)v.z + (double)v.w * (double)v.w;
#pragma unroll
    for (int off = 1; off < 64; off <<= 1)
      s += __shfl_xor(s, off, 64);
    if (lane == 0) p2[row] = s;
  }
}

// ---------------------------------------------------------------------------
// Phase 2 (dense, coalesced, 2 positions/thread): block = (b, 512-pos chunk).
// Thread owns positions sA, sA+256. Each LDS broadcast read of a proto value
// feeds 2 FMAs. fp64 accumulation, d-order 0..255 sequential per position ->
// argmin decisions identical to rounds 1/3 (verified absmax 0.0).
// Winning k written densely for all positions (scatter consults the mask).
// ---------------------------------------------------------------------------
__global__ __launch_bounds__(256) void argmin_kernel(
    const float* __restrict__ assp,
    const float* __restrict__ proto,
    const double* __restrict__ p2,
    signed char* __restrict__ table) {
  __shared__ double spd[D][K];    // 36 KiB

  const int b     = blockIdx.x & 15;   // spread batches across XCDs
  const int chunk = blockIdx.x >> 4;   // 0..31

  const float* pb = proto + (size_t)b * K * D;
  for (int i = threadIdx.x; i < K * D; i += 256)
    spd[i & 255][i >> 8] = (double)pb[i];
  __syncthreads();

  const int sA = chunk * 512 + threadIdx.x;          // position A
  const float* fA = assp + (size_t)b * D * S + sA;   // position B = sA + 256

  double accA[K], accB[K];
#pragma unroll
  for (int k = 0; k < K; ++k) { accA[k] = 0.0; accB[k] = 0.0; }

  for (int d = 0; d < D; d += 8) {
    float va[8], vb[8];
#pragma unroll
    for (int j = 0; j < 8; ++j) {                    // 16 coalesced loads in flight
      va[j] = fA[(size_t)(d + j) * S];
      vb[j] = fA[(size_t)(d + j) * S + 256];
    }
#pragma unroll
    for (int j = 0; j < 8; ++j) {
      const double a  = (double)va[j];
      const double bb = (double)vb[j];
      const double* pr = spd[d + j];                 // wave-uniform -> LDS broadcast
#pragma unroll
      for (int k = 0; k < K; ++k) {
        const double pk = pr[k];
        accA[k] += a * pk;
        accB[k] += bb * pk;
      }
    }
  }

  const double* p2b = p2 + (size_t)b * K;
  double bestA = 1e300, bestB = 1e300;
  int kA = 0, kB = 0;
#pragma unroll
  for (int k = 0; k < K; ++k) {
    const double dA = p2b[k] - 2.0 * accA[k];
    const double dB = p2b[k] - 2.0 * accB[k];
    if (dA < bestA) { bestA = dA; kA = k; }   // strict '<' = first-min (argmin)
    if (dB < bestB) { bestB = dB; kB = k; }
  }
  table[(size_t)b * S + sA]       = (signed char)kA;
  table[(size_t)b * S + sA + 256] = (signed char)kB;
}

// ---------------------------------------------------------------------------
// Phase 3: one block per (b,d) plane, walked d-DESCENDING (reverse of
// argmin's read-time order) so reads can hit the L3 tail left by argmin.
// Plain stores: nontemporal stores broke post-timing validation (round 4 —
// harness poisons d_out to 0xAA; nt no-allocate writes left stale L2 lines).
// ---------------------------------------------------------------------------
__global__ __launch_bounds__(256) void scatter_kernel(
    const float* __restrict__ assp,
    const float* __restrict__ proto,
    const signed char* __restrict__ table,
    const unsigned char* __restrict__ mask,
    float* __restrict__ out) {
  const int d  = 255 - (blockIdx.x >> 4);   // d descending across all b together
  const int b  = blockIdx.x & 15;
  const int bd = b * D + d;

  __shared__ float sp[K];
  if (threadIdx.x < K)
    sp[threadIdx.x] = proto[((size_t)b * K + threadIdx.x) * D + d];
  __syncthreads();

  const signed char* tb = table + (size_t)b * S;
  const float4* in4 = (const float4*)(assp + (size_t)bd * S);
  float4* out4 = (float4*)(out + (size_t)bd * S);

#pragma unroll
  for (int it = 0; it < S / 4 / 256; ++it) {   // 16 iterations
    const int i = it * 256 + threadIdx.x;      // float4 index within plane
    char4 t, m;
    *(int*)&t = ((const int*)tb)[i];
    *(int*)&m = ((const int*)mask)[i];
    float4 v = in4[i];
    if (m.x) v.x = sp[(int)t.x];
    if (m.y) v.y = sp[(int)t.y];
    if (m.z) v.z = sp[(int)t.z];
    if (m.w) v.w = sp[(int)t.w];
    out4[i] = v;
  }
}

extern "C" void kernel_launch(void* const* d_in, const int* in_sizes, int n_in,
                              void* d_out, int out_size, void* d_ws, size_t ws_size,
                              hipStream_t stream) {
  const float* assp  = (const float*)d_in[0];
  const float* proto = (const float*)d_in[1];
  const int*   idx   = (const int*)d_in[2];
  float* out = (float*)d_out;

  // ws layout: [table: B*S bytes][mask: S bytes][p2: B*K doubles]
  signed char*   table = (signed char*)d_ws;
  unsigned char* mask  = (unsigned char*)d_ws + (size_t)B * S;
  double*        p2    = (double*)((char*)d_ws + (size_t)B * S + S);

  hipMemsetAsync(mask, 0, S, stream);   // 16 KiB
  prep2_kernel<<<104, 256, 0, stream>>>(proto, idx, mask, p2);
  argmin_kernel<<<B * (S / 512), 256, 0, stream>>>(assp, proto, p2, table);
  scatter_kernel<<<B * D, 256, 0, stream>>>(assp, proto, table, mask, out);
}